// Round 14
// baseline (192.019 us; speedup 1.0000x reference)
//
#include <hip/hip_runtime.h>
#include <hip/hip_bf16.h>
#include <math.h>

#define B_ 32
#define N_ 16384
#define D_ 128
#define NEG_SLOPE 0.2f
#define CHUNKS 16      // 512 blocks = 2/CU
#define TILES 16       // 64-row tiles per chunk (16 rows per wave per tile)

typedef __attribute__((ext_vector_type(8))) short short8;
typedef __attribute__((ext_vector_type(4))) float f32x4;

__device__ __forceinline__ unsigned pk2(float lo, float hi) {
    union { __hip_bfloat162 b; unsigned u; } t;
    t.b = __float22bfloat162_rn(make_float2(lo, hi));
    return t.u;
}
__device__ __forceinline__ short8 pack8(float4 x, float4 y) {
    union { unsigned u[4]; short8 s; } r;
    r.u[0] = pk2(x.x, x.y); r.u[1] = pk2(x.z, x.w);
    r.u[2] = pk2(y.x, y.y); r.u[3] = pk2(y.z, y.w);
    return r.s;
}

// k-slot permutation (r12): lane (ln,g) holds k = kk*32 + g*4 + {0..3} and
// kk*32 + 16 + g*4 + {0..3}; per instruction the 4 g-lanes of a row are
// byte-contiguous -> full-64B-line coalescing. B fragments permuted identically.
#define ISSUE(tt, r) do {                                                   \
    const float* _src = rowp + (size_t)(tt) * 64 * D_;                      \
    _Pragma("unroll")                                                       \
    for (int kk = 0; kk < 4; ++kk) {                                        \
        (r)[2 * kk]     = *(const float4*)(_src + kk * 32);                 \
        (r)[2 * kk + 1] = *(const float4*)(_src + kk * 32 + 16);            \
    }                                                                       \
} while (0)

// consume raw; per-kk: pack 2 regs -> immediately reissue those 2 slots for
// tile tt+2 (TWO-tile-deep pipeline: prefetch distance 2 periods >> loaded
// latency, so packs never stall in steady state)
#define PROC(raw, tt) do {                                                  \
    f32x4 acc[8] = {};                                                      \
    _Pragma("unroll")                                                       \
    for (int kk = 0; kk < 4; ++kk) {                                        \
        short8 af = pack8((raw)[2 * kk], (raw)[2 * kk + 1]); /* vmcnt */    \
        if ((tt) + 2 < TILES) {                                             \
            const float* _src = rowp + (size_t)((tt) + 2) * 64 * D_;        \
            (raw)[2 * kk]     = *(const float4*)(_src + kk * 32);           \
            (raw)[2 * kk + 1] = *(const float4*)(_src + kk * 32 + 16);      \
        }                                                                   \
        _Pragma("unroll")                                                   \
        for (int cf = 0; cf < 8; ++cf) {                                    \
            short8 bq = *(const short8*)&wk[((cf * 4 + kk) * 64 + lane) * 8]; \
            acc[cf] = __builtin_amdgcn_mfma_f32_16x16x32_bf16(af, bq, acc[cf], 0, 0, 0); \
        }                                                                   \
    }                                                                       \
    float lg[4];                                                            \
    _Pragma("unroll")                                                       \
    for (int j = 0; j < 4; ++j) {                                           \
        float s = 0.f;                                                      \
        _Pragma("unroll")                                                   \
        for (int cf = 0; cf < 8; ++cf) {                                    \
            float v = hq_r[cf] + acc[cf][j];                                \
            v = (v > 0.f) ? v : (NEG_SLOPE * v);                            \
            s = fmaf(v, wa_r[cf], s);                                       \
        }                                                                   \
        s += __shfl_xor(s, 1);                                              \
        s += __shfl_xor(s, 2);                                              \
        s += __shfl_xor(s, 4);                                              \
        s += __shfl_xor(s, 8);                                              \
        lg[j] = s;                                                          \
    }                                                                       \
    {                                                                       \
        int nbase = n0 + (tt) * 64 + w * 16;                                \
        if (ln == 0)                                                        \
            *(float4*)&logits[(size_t)b * N_ + nbase + g * 4] =             \
                make_float4(lg[0], lg[1], lg[2], lg[3]);                    \
    }                                                                       \
    float mt = fmaxf(fmaxf(lg[0], lg[1]), fmaxf(lg[2], lg[3]));             \
    mt = fmaxf(mt, __shfl_xor(mt, 16));                                     \
    mt = fmaxf(mt, __shfl_xor(mt, 32));                                     \
    float m_new = fmaxf(m_w, mt);                                           \
    float corr = __expf(m_w - m_new);                                       \
    l_w *= corr;                                                            \
    _Pragma("unroll")                                                       \
    for (int cf = 0; cf < 8; ++cf) accl[cf] *= corr;                        \
    _Pragma("unroll")                                                       \
    for (int j = 0; j < 4; ++j) {                                           \
        float p = __expf(lg[j] - m_new);                                    \
        l_w += (ln == 0) ? p : 0.f;                                         \
        _Pragma("unroll")                                                   \
        for (int cf = 0; cf < 8; ++cf)                                      \
            accl[cf] = fmaf(p, acc[cf][j], accl[cf]);                       \
    }                                                                       \
    m_w = m_new;                                                            \
} while (0)

// ---- fused main: hq + h_key GEMM + logits + online softmax ----
// Key loads straight into A-fragment registers; TWO-tile-deep raw double
// buffer with per-kk smoothed reissue; Wk in LDS fragment-contiguous;
// barrier-free wave-private main loop; 2 blocks/CU (the only spill-free
// operating point: allocator splits unified file half arch / half AGPR).
__global__ __launch_bounds__(256, 2) void
main_kernel(const float* __restrict__ query, const float* __restrict__ key,
            const float* __restrict__ Wq, const float* __restrict__ Wk,
            const float* __restrict__ Wa,
            float* __restrict__ logits, float* __restrict__ part) {
    __shared__ unsigned short wk[32 * 64 * 8];  // 32 frags x 64 lanes x bf16x8 = 32 KB
    __shared__ float hq_lds[D_];
    __shared__ float comb_acc[4][D_];
    __shared__ float comb_m[4], comb_l[4];

    const int b = blockIdx.y, chunk = blockIdx.x;
    const int tid = threadIdx.x;
    const int w = tid >> 6, lane = tid & 63, ln = lane & 15, g = lane >> 4;
    const int n0 = chunk * (N_ / CHUNKS);

    // ---- fill Wk fragments into LDS (k-slot permuted to match ISSUE) ----
#pragma unroll
    for (int idx = tid; idx < 2048; idx += 256) {
        int f = idx >> 6, l = idx & 63;
        int c = (f >> 2) * 16 + (l & 15);
        int base = (f & 3) * 32 + (l >> 4) * 4;
        const float* wp = Wk + (size_t)c * D_ + base;
        float4 p0 = *(const float4*)(wp);
        float4 p1 = *(const float4*)(wp + 16);
        *(short8*)&wk[idx * 8] = pack8(p0, p1);
    }
    // ---- hq split across waves ----
    {
        const float4* qv = (const float4*)(query + (size_t)b * D_);
#pragma unroll
        for (int cc = 0; cc < 2; ++cc) {
            int cf = w * 2 + cc;
            const float4* wv = (const float4*)(Wq + (size_t)(cf * 16 + ln) * D_ + g * 32);
            float s = 0.f;
#pragma unroll
            for (int u = 0; u < 8; ++u) {
                float4 wq = wv[u], qq = qv[g * 8 + u];
                s = fmaf(wq.x, qq.x, s); s = fmaf(wq.y, qq.y, s);
                s = fmaf(wq.z, qq.z, s); s = fmaf(wq.w, qq.w, s);
            }
            s += __shfl_xor(s, 16);
            s += __shfl_xor(s, 32);
            if (lane < 16) hq_lds[cf * 16 + ln] = s;
        }
    }
    __syncthreads();   // the only barrier before the epilogue

    float hq_r[8], wa_r[8];
#pragma unroll
    for (int cf = 0; cf < 8; ++cf) {
        hq_r[cf] = hq_lds[cf * 16 + ln];
        wa_r[cf] = Wa[cf * 16 + ln];
    }

    float m_w = -1e30f, l_w = 0.f;
    float accl[8];
#pragma unroll
    for (int cf = 0; cf < 8; ++cf) accl[cf] = 0.f;

    const float* rowp = key + ((size_t)b * N_ + n0 + w * 16 + ln) * D_ + g * 4;

    float4 rawA[8], rawB[8];
    ISSUE(0, rawA);
    ISSUE(1, rawB);
    for (int t = 0; t < TILES; t += 2) {
        PROC(rawA, t);
        PROC(rawB, t + 1);
    }

    // ---- block combine (4 waves, disjoint row ranges) ----
#pragma unroll
    for (int cf = 0; cf < 8; ++cf) {
        accl[cf] += __shfl_xor(accl[cf], 16);
        accl[cf] += __shfl_xor(accl[cf], 32);
    }
    l_w += __shfl_xor(l_w, 1);
    l_w += __shfl_xor(l_w, 2);
    l_w += __shfl_xor(l_w, 4);
    l_w += __shfl_xor(l_w, 8);
    l_w += __shfl_xor(l_w, 16);
    l_w += __shfl_xor(l_w, 32);
    if (lane < 16) {
#pragma unroll
        for (int cf = 0; cf < 8; ++cf)
            comb_acc[w][cf * 16 + ln] = accl[cf];
    }
    if (lane == 0) { comb_m[w] = m_w; comb_l[w] = l_w; }
    __syncthreads();
    if (tid < D_ + 2) {
        float mb = fmaxf(fmaxf(comb_m[0], comb_m[1]), fmaxf(comb_m[2], comb_m[3]));
        float* pp = part + ((size_t)b * CHUNKS + chunk) * 132;
        if (tid < D_) {
            float ab = 0.f;
#pragma unroll
            for (int ww = 0; ww < 4; ++ww)
                ab = fmaf(comb_acc[ww][tid], __expf(comb_m[ww] - mb), ab);
            pp[2 + tid] = ab;
        } else if (tid == D_) {
            pp[0] = mb;
        } else {
            float lb = 0.f;
#pragma unroll
            for (int ww = 0; ww < 4; ++ww)
                lb = fmaf(comb_l[ww], __expf(comb_m[ww] - mb), lb);
            pp[1] = lb;
        }
    }
}

// ---- fused finish + e ----
__global__ __launch_bounds__(256) void
finish_e_kernel(const float* __restrict__ part, const float* __restrict__ logits,
                float* __restrict__ out) {
    const int b = blockIdx.y, s = blockIdx.x, t = threadIdx.x;
    float mb = -1e30f;
#pragma unroll
    for (int c = 0; c < CHUNKS; ++c)
        mb = fmaxf(mb, part[((size_t)b * CHUNKS + c) * 132]);
    float lb = 0.f;
#pragma unroll
    for (int c = 0; c < CHUNKS; ++c) {
        const float* pp = part + ((size_t)b * CHUNKS + c) * 132;
        lb = fmaf(pp[1], __expf(pp[0] - mb), lb);
    }
    if (s == 0 && t < D_) {
        float ac = 0.f;
#pragma unroll
        for (int c = 0; c < CHUNKS; ++c) {
            const float* pp = part + ((size_t)b * CHUNKS + c) * 132;
            ac = fmaf(pp[2 + t], __expf(pp[0] - mb), ac);
        }
        float sc = ac / lb;
        out[b * D_ + t] = (sc > 0.f) ? sc : expm1f(sc);
    }
    float inv = 1.f / lb;
    int n4 = s * 1024 + t * 4;
    float4 lg = *(const float4*)&logits[(size_t)b * N_ + n4];
    float4 e;
    e.x = __expf(lg.x - mb) * inv;
    e.y = __expf(lg.y - mb) * inv;
    e.z = __expf(lg.z - mb) * inv;
    e.w = __expf(lg.w - mb) * inv;
    *(float4*)&out[(size_t)B_ * D_ + (size_t)b * N_ + n4] = e;
}

extern "C" void kernel_launch(void* const* d_in, const int* in_sizes, int n_in,
                              void* d_out, int out_size, void* d_ws, size_t ws_size,
                              hipStream_t stream) {
    const float* query = (const float*)d_in[0];
    const float* key   = (const float*)d_in[1];
    const float* Wq    = (const float*)d_in[2];
    const float* Wk    = (const float*)d_in[3];
    const float* Wa    = (const float*)d_in[4];
    float* out = (float*)d_out;

    float* ws     = (float*)d_ws;
    float* logits = ws;                                   // B*N
    float* part   = logits + (size_t)B_ * N_;             // 32*16*132

    main_kernel<<<dim3(CHUNKS, B_), dim3(256), 0, stream>>>(
        query, key, Wq, Wk, Wa, logits, part);
    finish_e_kernel<<<dim3(16, B_), dim3(256), 0, stream>>>(part, logits, out);
}

// Round 16
// 101.986 us; speedup vs baseline: 1.8828x; 1.8828x over previous
//
#include <hip/hip_runtime.h>
#include <hip/hip_bf16.h>
#include <math.h>

#define B_ 32
#define N_ 16384
#define D_ 128
#define NEG_SLOPE 0.2f
#define CHUNKS 8       // 256 blocks = exactly 1/CU (persistent)
#define TILES 32       // 64-row tiles per chunk (2048 rows/chunk)
#define RING 6         // LDS ring depth (6 x 16 KB bf16 tiles)
#define NPROD 12       // producer waves; waves 12..15 are consumers

typedef __attribute__((ext_vector_type(8))) short short8;
typedef __attribute__((ext_vector_type(4))) float f32x4;

__device__ __forceinline__ unsigned pk2(float lo, float hi) {
    union { __hip_bfloat162 b; unsigned u; } t;
    t.b = __float22bfloat162_rn(make_float2(lo, hi));
    return t.u;
}
__device__ __forceinline__ short8 pack8(float4 x, float4 y) {
    union { unsigned u[4]; short8 s; } r;
    r.u[0] = pk2(x.x, x.y); r.u[1] = pk2(x.z, x.w);
    r.u[2] = pk2(y.x, y.y); r.u[3] = pk2(y.z, y.w);
    return r.s;
}

#define SPIN_GE(ptr, target)                                                \
    while (__hip_atomic_load((ptr), __ATOMIC_ACQUIRE,                       \
                             __HIP_MEMORY_SCOPE_WORKGROUP) < (target))      \
        __builtin_amdgcn_s_sleep(2)

// ONE flag increment per WAVE (r15 bug: per-lane atomics inflated counts 64x)
#define SIGNAL(ptr)                                                         \
    if (lane == 0) __hip_atomic_fetch_add((ptr), 1, __ATOMIC_RELEASE,       \
                                          __HIP_MEMORY_SCOPE_WORKGROUP)

// producer: pack one dwordx4 load (1 KB across wave = 2 rows) into ring slot
#define PWRITE(rs, v, i) do {                                               \
    int _row = 2 * (i) + (lane >> 5);                                       \
    unsigned _a = ((unsigned)(_row * 256 + (lane & 31) * 8)) ^              \
                  (((unsigned)(_row & 7)) << 4);                            \
    uint2 _pk; _pk.x = pk2((v).x, (v).y); _pk.y = pk2((v).z, (v).w);        \
    *(uint2*)((rs) + _a) = _pk;                                             \
} while (0)

#define PLOAD(tt, r0, r1, r2) do {                                          \
    const char* _gt = gt0 + (size_t)(tt) * 32768;                           \
    r0 = *(const float4*)(_gt + (size_t)(p) * 1024 + lane * 16);            \
    r1 = *(const float4*)(_gt + (size_t)(p + 12) * 1024 + lane * 16);       \
    if (three) r2 = *(const float4*)(_gt + (size_t)(p + 24) * 1024 + lane * 16); \
} while (0)

#define PSTORE(tt, r0, r1, r2) do {                                         \
    int _s = (tt) % RING, _r = (tt) / RING;                                 \
    if (_r > 0) SPIN_GE(&flags[RING + _s], 4 * _r);                         \
    char* _rs = &ring[_s][0];                                               \
    PWRITE(_rs, r0, p);                                                     \
    PWRITE(_rs, r1, p + 12);                                                \
    if (three) PWRITE(_rs, r2, p + 24);                                     \
    SIGNAL(&flags[_s]);                                                     \
} while (0)

// ---- persistent producer/consumer kernel ----
// 1 block/CU, 16 waves: 12 producers stream key (double-buffered reg staging
// -> bf16 -> XOR-swizzled LDS ring), 4 consumers do MFMA + logits + online
// softmax. Sync: cumulative LDS flags, ONE add per wave, elastic ring.
__global__ __launch_bounds__(1024, 1) void
main_kernel(const float* __restrict__ query, const float* __restrict__ key,
            const float* __restrict__ Wq, const float* __restrict__ Wk,
            const float* __restrict__ Wa,
            float* __restrict__ logits, float* __restrict__ part) {
    __shared__ unsigned short wk[32 * 64 * 8];   // 32 KB Wk fragments
    __shared__ char ring[RING][16384];           // 96 KB key ring (bf16, swizzled)
    __shared__ float hq_lds[D_];
    __shared__ float comb_acc[4][D_];
    __shared__ float comb_m[4], comb_l[4];
    __shared__ int flags[2 * RING];              // [0..5]=produced, [6..11]=consumed

    const int b = blockIdx.y, chunk = blockIdx.x;
    const int tid = threadIdx.x;
    const int w = tid >> 6, lane = tid & 63, ln = lane & 15, g = lane >> 4;
    const int n0 = chunk * (N_ / CHUNKS);
    const bool isCons = (w >= NPROD);
    const int c = w - NPROD;                      // consumer index 0..3

    // ---- wk fill (all 16 waves) ----
#pragma unroll
    for (int idx = tid; idx < 2048; idx += 1024) {
        int f = idx >> 6, l = idx & 63;
        int cc = (f >> 2) * 16 + (l & 15);
        int k0 = (f & 3) * 32 + (l >> 4) * 8;
        const float4* pw = (const float4*)(Wk + (size_t)cc * D_ + k0);
        *(short8*)&wk[idx * 8] = pack8(pw[0], pw[1]);
    }
    // ---- hq (consumer waves, 2 cols-of-16 each) ----
    if (isCons) {
        const float4* qv = (const float4*)(query + (size_t)b * D_);
#pragma unroll
        for (int cc = 0; cc < 2; ++cc) {
            int cf = c * 2 + cc;
            const float4* wv = (const float4*)(Wq + (size_t)(cf * 16 + ln) * D_ + g * 32);
            float s = 0.f;
#pragma unroll
            for (int u = 0; u < 8; ++u) {
                float4 wq = wv[u], qq = qv[g * 8 + u];
                s = fmaf(wq.x, qq.x, s); s = fmaf(wq.y, qq.y, s);
                s = fmaf(wq.z, qq.z, s); s = fmaf(wq.w, qq.w, s);
            }
            s += __shfl_xor(s, 16);
            s += __shfl_xor(s, 32);
            if (lane < 16) hq_lds[cf * 16 + ln] = s;
        }
    }
    if (tid < 2 * RING) flags[tid] = 0;
    __syncthreads();

    if (!isCons) {
        // ================= PRODUCER =================
        const int p = w;
        const char* gt0 = (const char*)(key + ((size_t)b * N_ + n0) * D_);
        const bool three = (p < 8);              // p<8: rows {p,p+12,p+24}; else {p,p+12}
        float4 a0, a1, a2, b0, b1, b2;
        PLOAD(0, a0, a1, a2);
        for (int t = 0; t < TILES; t += 2) {
            PLOAD(t + 1, b0, b1, b2);            // issue next-tile loads early
            PSTORE(t, a0, a1, a2);
            if (t + 2 < TILES) PLOAD(t + 2, a0, a1, a2);
            PSTORE(t + 1, b0, b1, b2);
        }
    } else {
        // ================= CONSUMER =================
        float hq_r[8], wa_r[8];
#pragma unroll
        for (int cf = 0; cf < 8; ++cf) {
            hq_r[cf] = hq_lds[cf * 16 + ln];
            wa_r[cf] = Wa[cf * 16 + ln];
        }
        float m_w = -1e30f, l_w = 0.f;
        float accl[8];
#pragma unroll
        for (int cf = 0; cf < 8; ++cf) accl[cf] = 0.f;

        const int row = c * 16 + ln;
        const unsigned abase = (unsigned)(row * 256);
        const unsigned sw = ((unsigned)(ln & 7)) << 4;

        for (int t = 0; t < TILES; ++t) {
            const int s = t % RING;
            SPIN_GE(&flags[s], 12 * (t / RING) + 12);
            const char* rs = &ring[s][0];
            f32x4 acc[8] = {};
#pragma unroll
            for (int kk = 0; kk < 4; ++kk) {
                short8 af = *(const short8*)(rs +
                    ((abase + kk * 64 + g * 16) ^ sw));
#pragma unroll
                for (int cf = 0; cf < 8; ++cf) {
                    short8 bq = *(const short8*)&wk[((cf * 4 + kk) * 64 + lane) * 8];
                    acc[cf] = __builtin_amdgcn_mfma_f32_16x16x32_bf16(af, bq, acc[cf], 0, 0, 0);
                }
            }
            SIGNAL(&flags[RING + s]);
            // logits: lrelu(hq + h_key) . Wa, 16-lane reduce
            float lg[4];
#pragma unroll
            for (int j = 0; j < 4; ++j) {
                float sacc = 0.f;
#pragma unroll
                for (int cf = 0; cf < 8; ++cf) {
                    float v = hq_r[cf] + acc[cf][j];
                    v = (v > 0.f) ? v : (NEG_SLOPE * v);
                    sacc = fmaf(v, wa_r[cf], sacc);
                }
                sacc += __shfl_xor(sacc, 1);
                sacc += __shfl_xor(sacc, 2);
                sacc += __shfl_xor(sacc, 4);
                sacc += __shfl_xor(sacc, 8);
                lg[j] = sacc;
            }
            int nbase = n0 + t * 64 + c * 16;
            if (ln == 0)
                *(float4*)&logits[(size_t)b * N_ + nbase + g * 4] =
                    make_float4(lg[0], lg[1], lg[2], lg[3]);
            // online softmax accumulate
            float mt = fmaxf(fmaxf(lg[0], lg[1]), fmaxf(lg[2], lg[3]));
            mt = fmaxf(mt, __shfl_xor(mt, 16));
            mt = fmaxf(mt, __shfl_xor(mt, 32));
            float m_new = fmaxf(m_w, mt);
            float corr = __expf(m_w - m_new);
            l_w *= corr;
#pragma unroll
            for (int cf = 0; cf < 8; ++cf) accl[cf] *= corr;
#pragma unroll
            for (int j = 0; j < 4; ++j) {
                float pe = __expf(lg[j] - m_new);
                l_w += (ln == 0) ? pe : 0.f;
#pragma unroll
                for (int cf = 0; cf < 8; ++cf)
                    accl[cf] = fmaf(pe, acc[cf][j], accl[cf]);
            }
            m_w = m_new;
        }
        // consumer wave-local reduce -> comb
#pragma unroll
        for (int cf = 0; cf < 8; ++cf) {
            accl[cf] += __shfl_xor(accl[cf], 16);
            accl[cf] += __shfl_xor(accl[cf], 32);
        }
        l_w += __shfl_xor(l_w, 1);
        l_w += __shfl_xor(l_w, 2);
        l_w += __shfl_xor(l_w, 4);
        l_w += __shfl_xor(l_w, 8);
        l_w += __shfl_xor(l_w, 16);
        l_w += __shfl_xor(l_w, 32);
        if (lane < 16) {
#pragma unroll
            for (int cf = 0; cf < 8; ++cf)
                comb_acc[c][cf * 16 + ln] = accl[cf];
        }
        if (lane == 0) { comb_m[c] = m_w; comb_l[c] = l_w; }
    }

    __syncthreads();
    if (tid < D_ + 2) {
        float mb = fmaxf(fmaxf(comb_m[0], comb_m[1]), fmaxf(comb_m[2], comb_m[3]));
        float* pp = part + ((size_t)b * CHUNKS + chunk) * 132;
        if (tid < D_) {
            float ab = 0.f;
#pragma unroll
            for (int ww = 0; ww < 4; ++ww)
                ab = fmaf(comb_acc[ww][tid], __expf(comb_m[ww] - mb), ab);
            pp[2 + tid] = ab;
        } else if (tid == D_) {
            pp[0] = mb;
        } else {
            float lb = 0.f;
#pragma unroll
            for (int ww = 0; ww < 4; ++ww)
                lb = fmaf(comb_l[ww], __expf(comb_m[ww] - mb), lb);
            pp[1] = lb;
        }
    }
}

// ---- fused finish + e ----
__global__ __launch_bounds__(256) void
finish_e_kernel(const float* __restrict__ part, const float* __restrict__ logits,
                float* __restrict__ out) {
    const int b = blockIdx.y, s = blockIdx.x, t = threadIdx.x;
    float mb = -1e30f;
#pragma unroll
    for (int c = 0; c < CHUNKS; ++c)
        mb = fmaxf(mb, part[((size_t)b * CHUNKS + c) * 132]);
    float lb = 0.f;
#pragma unroll
    for (int c = 0; c < CHUNKS; ++c) {
        const float* pp = part + ((size_t)b * CHUNKS + c) * 132;
        lb = fmaf(pp[1], __expf(pp[0] - mb), lb);
    }
    if (s == 0 && t < D_) {
        float ac = 0.f;
#pragma unroll
        for (int c = 0; c < CHUNKS; ++c) {
            const float* pp = part + ((size_t)b * CHUNKS + c) * 132;
            ac = fmaf(pp[2 + t], __expf(pp[0] - mb), ac);
        }
        float sc = ac / lb;
        out[b * D_ + t] = (sc > 0.f) ? sc : expm1f(sc);
    }
    float inv = 1.f / lb;
    int n4 = s * 1024 + t * 4;
    float4 lg = *(const float4*)&logits[(size_t)b * N_ + n4];
    float4 e;
    e.x = __expf(lg.x - mb) * inv;
    e.y = __expf(lg.y - mb) * inv;
    e.z = __expf(lg.z - mb) * inv;
    e.w = __expf(lg.w - mb) * inv;
    *(float4*)&out[(size_t)B_ * D_ + (size_t)b * N_ + n4] = e;
}

extern "C" void kernel_launch(void* const* d_in, const int* in_sizes, int n_in,
                              void* d_out, int out_size, void* d_ws, size_t ws_size,
                              hipStream_t stream) {
    const float* query = (const float*)d_in[0];
    const float* key   = (const float*)d_in[1];
    const float* Wq    = (const float*)d_in[2];
    const float* Wk    = (const float*)d_in[3];
    const float* Wa    = (const float*)d_in[4];
    float* out = (float*)d_out;

    float* ws     = (float*)d_ws;
    float* logits = ws;                                   // B*N
    float* part   = logits + (size_t)B_ * N_;             // 32*8*132

    main_kernel<<<dim3(CHUNKS, B_), dim3(1024), 0, stream>>>(
        query, key, Wq, Wk, Wa, logits, part);
    finish_e_kernel<<<dim3(16, B_), dim3(256), 0, stream>>>(part, logits, out);
}

// Round 18
// 77.863 us; speedup vs baseline: 2.4661x; 1.3098x over previous
//
#include <hip/hip_runtime.h>
#include <hip/hip_bf16.h>
#include <math.h>

#define B_ 32
#define N_ 16384
#define D_ 128
#define NEG_SLOPE 0.2f
#define CHUNKS 16      // 512 blocks = 2/CU
#define TILES 16       // 64-row tiles per chunk (16 rows per wave per tile)

typedef __attribute__((ext_vector_type(8))) short short8;
typedef __attribute__((ext_vector_type(4))) float f32x4;

__device__ __forceinline__ unsigned pk2(float lo, float hi) {
    union { __hip_bfloat162 b; unsigned u; } t;
    t.b = __float22bfloat162_rn(make_float2(lo, hi));
    return t.u;
}
__device__ __forceinline__ short8 pack8(float4 x, float4 y) {
    union { unsigned u[4]; short8 s; } r;
    r.u[0] = pk2(x.x, x.y); r.u[1] = pk2(x.z, x.w);
    r.u[2] = pk2(y.x, y.y); r.u[3] = pk2(y.z, y.w);
    return r.s;
}
__device__ __forceinline__ short8 pack8v(f32x4 x, f32x4 y) {
    union { unsigned u[4]; short8 s; } r;
    r.u[0] = pk2(x[0], x[1]); r.u[1] = pk2(x[2], x[3]);
    r.u[2] = pk2(y[0], y[1]); r.u[3] = pk2(y[2], y[3]);
    return r.s;
}

// issue tile tt's 8 global loads (nontemporal: stream-once data, no cache
// allocation) for this lane into reg buffer r[8]
#define ISSUE(tt, r) do {                                                   \
    const f32x4* _src = (const f32x4*)(rowp + (size_t)(tt) * 64 * D_);      \
    _Pragma("unroll")                                                       \
    for (int kk = 0; kk < 4; ++kk) {                                        \
        (r)[2 * kk]     = __builtin_nontemporal_load(_src + kk * 8);        \
        (r)[2 * kk + 1] = __builtin_nontemporal_load(_src + kk * 8 + 1);    \
    }                                                                       \
} while (0)

// consume raw; per-kk: pack 2 regs -> immediately reissue those 2 slots for
// tile tt+1 (smooth issue, full-tile-period latency budget per load)
#define PROC(raw, tt) do {                                                  \
    f32x4 acc[8] = {};                                                      \
    _Pragma("unroll")                                                       \
    for (int kk = 0; kk < 4; ++kk) {                                        \
        short8 af = pack8v((raw)[2 * kk], (raw)[2 * kk + 1]); /* vmcnt */   \
        if ((tt) + 1 < TILES) {                                             \
            const f32x4* _src = (const f32x4*)(rowp + (size_t)((tt) + 1) * 64 * D_); \
            (raw)[2 * kk]     = __builtin_nontemporal_load(_src + kk * 8);  \
            (raw)[2 * kk + 1] = __builtin_nontemporal_load(_src + kk * 8 + 1); \
        }                                                                   \
        _Pragma("unroll")                                                   \
        for (int cf = 0; cf < 8; ++cf) {                                    \
            short8 bq = *(const short8*)&wk[((cf * 4 + kk) * 64 + lane) * 8]; \
            acc[cf] = __builtin_amdgcn_mfma_f32_16x16x32_bf16(af, bq, acc[cf], 0, 0, 0); \
        }                                                                   \
    }                                                                       \
    float lg[4];                                                            \
    _Pragma("unroll")                                                       \
    for (int j = 0; j < 4; ++j) {                                           \
        float s = 0.f;                                                      \
        _Pragma("unroll")                                                   \
        for (int cf = 0; cf < 8; ++cf) {                                    \
            float v = hq_r[cf] + acc[cf][j];                                \
            v = (v > 0.f) ? v : (NEG_SLOPE * v);                            \
            s = fmaf(v, wa_r[cf], s);                                       \
        }                                                                   \
        s += __shfl_xor(s, 1);                                              \
        s += __shfl_xor(s, 2);                                              \
        s += __shfl_xor(s, 4);                                              \
        s += __shfl_xor(s, 8);                                              \
        lg[j] = s;                                                          \
    }                                                                       \
    {                                                                       \
        int nbase = n0 + (tt) * 64 + w * 16;                                \
        if (ln == 0)                                                        \
            *(float4*)&logits[(size_t)b * N_ + nbase + g * 4] =             \
                make_float4(lg[0], lg[1], lg[2], lg[3]);                    \
    }                                                                       \
    float mt = fmaxf(fmaxf(lg[0], lg[1]), fmaxf(lg[2], lg[3]));             \
    mt = fmaxf(mt, __shfl_xor(mt, 16));                                     \
    mt = fmaxf(mt, __shfl_xor(mt, 32));                                     \
    float m_new = fmaxf(m_w, mt);                                           \
    float corr = __expf(m_w - m_new);                                       \
    l_w *= corr;                                                            \
    _Pragma("unroll")                                                       \
    for (int cf = 0; cf < 8; ++cf) accl[cf] *= corr;                        \
    _Pragma("unroll")                                                       \
    for (int j = 0; j < 4; ++j) {                                           \
        float p = __expf(lg[j] - m_new);                                    \
        l_w += (ln == 0) ? p : 0.f;                                         \
        _Pragma("unroll")                                                   \
        for (int cf = 0; cf < 8; ++cf)                                      \
            accl[cf] = fmaf(p, acc[cf][j], accl[cf]);                       \
    }                                                                       \
    m_w = m_new;                                                            \
} while (0)

// ---- fused main: hq + h_key GEMM + logits + online softmax ----
// r11 structure (best: 68.6 us) + nontemporal key loads. Key loads straight
// into A-fragment registers (single tile-ahead, per-kk smoothed reissue,
// compiler-counted vmcnt). Wk in LDS fragment-contiguous. Barrier-free
// wave-private main loop. Two launches (no device fences).
__global__ __launch_bounds__(256, 2) void
main_kernel(const float* __restrict__ query, const float* __restrict__ key,
            const float* __restrict__ Wq, const float* __restrict__ Wk,
            const float* __restrict__ Wa,
            float* __restrict__ logits, float* __restrict__ part) {
    __shared__ unsigned short wk[32 * 64 * 8];  // 32 frags x 64 lanes x bf16x8 = 32 KB
    __shared__ float hq_lds[D_];
    __shared__ float comb_acc[4][D_];
    __shared__ float comb_m[4], comb_l[4];

    const int b = blockIdx.y, chunk = blockIdx.x;
    const int tid = threadIdx.x;
    const int w = tid >> 6, lane = tid & 63, ln = lane & 15, g = lane >> 4;
    const int n0 = chunk * (N_ / CHUNKS);

    // ---- fill Wk fragments into LDS ----
#pragma unroll
    for (int idx = tid; idx < 2048; idx += 256) {
        int f = idx >> 6, l = idx & 63;
        int c = (f >> 2) * 16 + (l & 15);
        int k0 = (f & 3) * 32 + (l >> 4) * 8;
        const float4* p = (const float4*)(Wk + (size_t)c * D_ + k0);
        *(short8*)&wk[idx * 8] = pack8(p[0], p[1]);
    }
    // ---- hq split across waves ----
    {
        const float4* qv = (const float4*)(query + (size_t)b * D_);
#pragma unroll
        for (int cc = 0; cc < 2; ++cc) {
            int cf = w * 2 + cc;
            const float4* wv = (const float4*)(Wq + (size_t)(cf * 16 + ln) * D_ + g * 32);
            float s = 0.f;
#pragma unroll
            for (int u = 0; u < 8; ++u) {
                float4 wq = wv[u], qq = qv[g * 8 + u];
                s = fmaf(wq.x, qq.x, s); s = fmaf(wq.y, qq.y, s);
                s = fmaf(wq.z, qq.z, s); s = fmaf(wq.w, qq.w, s);
            }
            s += __shfl_xor(s, 16);
            s += __shfl_xor(s, 32);
            if (lane < 16) hq_lds[cf * 16 + ln] = s;
        }
    }
    __syncthreads();   // the only barrier before the epilogue

    float hq_r[8], wa_r[8];
#pragma unroll
    for (int cf = 0; cf < 8; ++cf) {
        hq_r[cf] = hq_lds[cf * 16 + ln];
        wa_r[cf] = Wa[cf * 16 + ln];
    }

    float m_w = -1e30f, l_w = 0.f;
    float accl[8];
#pragma unroll
    for (int cf = 0; cf < 8; ++cf) accl[cf] = 0.f;

    const float* rowp = key + ((size_t)b * N_ + n0 + w * 16 + ln) * D_ + g * 8;

    f32x4 raw[8];
    ISSUE(0, raw);
    for (int t = 0; t < TILES; ++t) {
        PROC(raw, t);
    }

    // ---- block combine (4 waves, disjoint row ranges) ----
#pragma unroll
    for (int cf = 0; cf < 8; ++cf) {
        accl[cf] += __shfl_xor(accl[cf], 16);
        accl[cf] += __shfl_xor(accl[cf], 32);
    }
    l_w += __shfl_xor(l_w, 1);
    l_w += __shfl_xor(l_w, 2);
    l_w += __shfl_xor(l_w, 4);
    l_w += __shfl_xor(l_w, 8);
    l_w += __shfl_xor(l_w, 16);
    l_w += __shfl_xor(l_w, 32);
    if (lane < 16) {
#pragma unroll
        for (int cf = 0; cf < 8; ++cf)
            comb_acc[w][cf * 16 + ln] = accl[cf];
    }
    if (lane == 0) { comb_m[w] = m_w; comb_l[w] = l_w; }
    __syncthreads();
    if (tid < D_ + 2) {
        float mb = fmaxf(fmaxf(comb_m[0], comb_m[1]), fmaxf(comb_m[2], comb_m[3]));
        float* pp = part + ((size_t)b * CHUNKS + chunk) * 132;
        if (tid < D_) {
            float ab = 0.f;
#pragma unroll
            for (int ww = 0; ww < 4; ++ww)
                ab = fmaf(comb_acc[ww][tid], __expf(comb_m[ww] - mb), ab);
            pp[2 + tid] = ab;
        } else if (tid == D_) {
            pp[0] = mb;
        } else {
            float lb = 0.f;
#pragma unroll
            for (int ww = 0; ww < 4; ++ww)
                lb = fmaf(comb_l[ww], __expf(comb_m[ww] - mb), lb);
            pp[1] = lb;
        }
    }
}

// ---- fused finish + e ----
__global__ __launch_bounds__(256) void
finish_e_kernel(const float* __restrict__ part, const float* __restrict__ logits,
                float* __restrict__ out) {
    const int b = blockIdx.y, s = blockIdx.x, t = threadIdx.x;
    float mb = -1e30f;
#pragma unroll
    for (int c = 0; c < CHUNKS; ++c)
        mb = fmaxf(mb, part[((size_t)b * CHUNKS + c) * 132]);
    float lb = 0.f;
#pragma unroll
    for (int c = 0; c < CHUNKS; ++c) {
        const float* pp = part + ((size_t)b * CHUNKS + c) * 132;
        lb = fmaf(pp[1], __expf(pp[0] - mb), lb);
    }
    if (s == 0 && t < D_) {
        float ac = 0.f;
#pragma unroll
        for (int c = 0; c < CHUNKS; ++c) {
            const float* pp = part + ((size_t)b * CHUNKS + c) * 132;
            ac = fmaf(pp[2 + t], __expf(pp[0] - mb), ac);
        }
        float sc = ac / lb;
        out[b * D_ + t] = (sc > 0.f) ? sc : expm1f(sc);
    }
    float inv = 1.f / lb;
    int n4 = s * 1024 + t * 4;
    float4 lg = *(const float4*)&logits[(size_t)b * N_ + n4];
    float4 e;
    e.x = __expf(lg.x - mb) * inv;
    e.y = __expf(lg.y - mb) * inv;
    e.z = __expf(lg.z - mb) * inv;
    e.w = __expf(lg.w - mb) * inv;
    *(float4*)&out[(size_t)B_ * D_ + (size_t)b * N_ + n4] = e;
}

extern "C" void kernel_launch(void* const* d_in, const int* in_sizes, int n_in,
                              void* d_out, int out_size, void* d_ws, size_t ws_size,
                              hipStream_t stream) {
    const float* query = (const float*)d_in[0];
    const float* key   = (const float*)d_in[1];
    const float* Wq    = (const float*)d_in[2];
    const float* Wk    = (const float*)d_in[3];
    const float* Wa    = (const float*)d_in[4];
    float* out = (float*)d_out;

    float* ws     = (float*)d_ws;
    float* logits = ws;                                   // B*N
    float* part   = logits + (size_t)B_ * N_;             // 32*16*132

    main_kernel<<<dim3(CHUNKS, B_), dim3(256), 0, stream>>>(
        query, key, Wq, Wk, Wa, logits, part);
    finish_e_kernel<<<dim3(16, B_), dim3(256), 0, stream>>>(part, logits, out);
}

// Round 19
// 68.184 us; speedup vs baseline: 2.8162x; 1.1420x over previous
//
#include <hip/hip_runtime.h>
#include <hip/hip_bf16.h>
#include <math.h>

#define B_ 32
#define N_ 16384
#define D_ 128
#define NEG_SLOPE 0.2f
#define CHUNKS 16      // 512 blocks = 2/CU
#define TILES 16       // 64-row tiles per chunk (16 rows per wave per tile)

typedef __attribute__((ext_vector_type(8))) short short8;
typedef __attribute__((ext_vector_type(4))) float f32x4;

__device__ __forceinline__ unsigned pk2(float lo, float hi) {
    union { __hip_bfloat162 b; unsigned u; } t;
    t.b = __float22bfloat162_rn(make_float2(lo, hi));
    return t.u;
}
__device__ __forceinline__ short8 pack8(float4 x, float4 y) {
    union { unsigned u[4]; short8 s; } r;
    r.u[0] = pk2(x.x, x.y); r.u[1] = pk2(x.z, x.w);
    r.u[2] = pk2(y.x, y.y); r.u[3] = pk2(y.z, y.w);
    return r.s;
}

// issue tile tt's 8 global loads for this lane into reg buffer r[8]
#define ISSUE(tt, r) do {                                                   \
    const float* _src = rowp + (size_t)(tt) * 64 * D_;                      \
    _Pragma("unroll")                                                       \
    for (int kk = 0; kk < 4; ++kk) {                                        \
        (r)[2 * kk]     = *(const float4*)(_src + kk * 32);                 \
        (r)[2 * kk + 1] = *(const float4*)(_src + kk * 32 + 4);             \
    }                                                                       \
} while (0)

// consume raw; per-kk: pack 2 regs -> immediately reissue those 2 slots for
// tile tt+1 (smooth issue, full-tile-period latency budget per load)
#define PROC(raw, tt) do {                                                  \
    f32x4 acc[8] = {};                                                      \
    _Pragma("unroll")                                                       \
    for (int kk = 0; kk < 4; ++kk) {                                        \
        short8 af = pack8((raw)[2 * kk], (raw)[2 * kk + 1]); /* vmcnt */    \
        if ((tt) + 1 < TILES) {                                             \
            const float* _src = rowp + (size_t)((tt) + 1) * 64 * D_;        \
            (raw)[2 * kk]     = *(const float4*)(_src + kk * 32);           \
            (raw)[2 * kk + 1] = *(const float4*)(_src + kk * 32 + 4);       \
        }                                                                   \
        _Pragma("unroll")                                                   \
        for (int cf = 0; cf < 8; ++cf) {                                    \
            short8 bq = *(const short8*)&wk[((cf * 4 + kk) * 64 + lane) * 8]; \
            acc[cf] = __builtin_amdgcn_mfma_f32_16x16x32_bf16(af, bq, acc[cf], 0, 0, 0); \
        }                                                                   \
    }                                                                       \
    float lg[4];                                                            \
    _Pragma("unroll")                                                       \
    for (int j = 0; j < 4; ++j) {                                           \
        float s = 0.f;                                                      \
        _Pragma("unroll")                                                   \
        for (int cf = 0; cf < 8; ++cf) {                                    \
            float v = hq_r[cf] + acc[cf][j];                                \
            v = (v > 0.f) ? v : (NEG_SLOPE * v);                            \
            s = fmaf(v, wa_r[cf], s);                                       \
        }                                                                   \
        s += __shfl_xor(s, 1);                                              \
        s += __shfl_xor(s, 2);                                              \
        s += __shfl_xor(s, 4);                                              \
        s += __shfl_xor(s, 8);                                              \
        lg[j] = s;                                                          \
    }                                                                       \
    {                                                                       \
        int nbase = n0 + (tt) * 64 + w * 16;                                \
        if (ln == 0)                                                        \
            *(float4*)&logits[(size_t)b * N_ + nbase + g * 4] =             \
                make_float4(lg[0], lg[1], lg[2], lg[3]);                    \
    }                                                                       \
    float mt = fmaxf(fmaxf(lg[0], lg[1]), fmaxf(lg[2], lg[3]));             \
    mt = fmaxf(mt, __shfl_xor(mt, 16));                                     \
    mt = fmaxf(mt, __shfl_xor(mt, 32));                                     \
    float m_new = fmaxf(m_w, mt);                                           \
    float corr = __expf(m_w - m_new);                                       \
    l_w *= corr;                                                            \
    _Pragma("unroll")                                                       \
    for (int cf = 0; cf < 8; ++cf) accl[cf] *= corr;                        \
    _Pragma("unroll")                                                       \
    for (int j = 0; j < 4; ++j) {                                           \
        float p = __expf(lg[j] - m_new);                                    \
        l_w += (ln == 0) ? p : 0.f;                                         \
        _Pragma("unroll")                                                   \
        for (int cf = 0; cf < 8; ++cf)                                      \
            accl[cf] = fmaf(p, acc[cf][j], accl[cf]);                       \
    }                                                                       \
    m_w = m_new;                                                            \
} while (0)

// ---- fused main: hq + h_key GEMM + logits + online softmax ----
// Key loads straight into A-fragment registers (plain global loads, single
// tile-ahead, per-kk smoothed reissue, compiler-counted vmcnt). Wk in LDS
// fragment-contiguous (conflict-free ds_read_b128). Barrier-free wave-private
// main loop. Two-launch structure (no device fences).
__global__ __launch_bounds__(256, 2) void
main_kernel(const float* __restrict__ query, const float* __restrict__ key,
            const float* __restrict__ Wq, const float* __restrict__ Wk,
            const float* __restrict__ Wa,
            float* __restrict__ logits, float* __restrict__ part) {
    __shared__ unsigned short wk[32 * 64 * 8];  // 32 frags x 64 lanes x bf16x8 = 32 KB
    __shared__ float hq_lds[D_];
    __shared__ float comb_acc[4][D_];
    __shared__ float comb_m[4], comb_l[4];

    const int b = blockIdx.y, chunk = blockIdx.x;
    const int tid = threadIdx.x;
    const int w = tid >> 6, lane = tid & 63, ln = lane & 15, g = lane >> 4;
    const int n0 = chunk * (N_ / CHUNKS);

    // ---- fill Wk fragments into LDS ----
#pragma unroll
    for (int idx = tid; idx < 2048; idx += 256) {
        int f = idx >> 6, l = idx & 63;
        int c = (f >> 2) * 16 + (l & 15);
        int k0 = (f & 3) * 32 + (l >> 4) * 8;
        const float4* p = (const float4*)(Wk + (size_t)c * D_ + k0);
        *(short8*)&wk[idx * 8] = pack8(p[0], p[1]);
    }
    // ---- hq split across waves ----
    {
        const float4* qv = (const float4*)(query + (size_t)b * D_);
#pragma unroll
        for (int cc = 0; cc < 2; ++cc) {
            int cf = w * 2 + cc;
            const float4* wv = (const float4*)(Wq + (size_t)(cf * 16 + ln) * D_ + g * 32);
            float s = 0.f;
#pragma unroll
            for (int u = 0; u < 8; ++u) {
                float4 wq = wv[u], qq = qv[g * 8 + u];
                s = fmaf(wq.x, qq.x, s); s = fmaf(wq.y, qq.y, s);
                s = fmaf(wq.z, qq.z, s); s = fmaf(wq.w, qq.w, s);
            }
            s += __shfl_xor(s, 16);
            s += __shfl_xor(s, 32);
            if (lane < 16) hq_lds[cf * 16 + ln] = s;
        }
    }
    __syncthreads();   // the only barrier before the epilogue

    float hq_r[8], wa_r[8];
#pragma unroll
    for (int cf = 0; cf < 8; ++cf) {
        hq_r[cf] = hq_lds[cf * 16 + ln];
        wa_r[cf] = Wa[cf * 16 + ln];
    }

    float m_w = -1e30f, l_w = 0.f;
    float accl[8];
#pragma unroll
    for (int cf = 0; cf < 8; ++cf) accl[cf] = 0.f;

    const float* rowp = key + ((size_t)b * N_ + n0 + w * 16 + ln) * D_ + g * 8;

    float4 raw[8];
    ISSUE(0, raw);
    for (int t = 0; t < TILES; ++t) {
        PROC(raw, t);
    }

    // ---- block combine (4 waves, disjoint row ranges) ----
#pragma unroll
    for (int cf = 0; cf < 8; ++cf) {
        accl[cf] += __shfl_xor(accl[cf], 16);
        accl[cf] += __shfl_xor(accl[cf], 32);
    }
    l_w += __shfl_xor(l_w, 1);
    l_w += __shfl_xor(l_w, 2);
    l_w += __shfl_xor(l_w, 4);
    l_w += __shfl_xor(l_w, 8);
    l_w += __shfl_xor(l_w, 16);
    l_w += __shfl_xor(l_w, 32);
    if (lane < 16) {
#pragma unroll
        for (int cf = 0; cf < 8; ++cf)
            comb_acc[w][cf * 16 + ln] = accl[cf];
    }
    if (lane == 0) { comb_m[w] = m_w; comb_l[w] = l_w; }
    __syncthreads();
    if (tid < D_ + 2) {
        float mb = fmaxf(fmaxf(comb_m[0], comb_m[1]), fmaxf(comb_m[2], comb_m[3]));
        float* pp = part + ((size_t)b * CHUNKS + chunk) * 132;
        if (tid < D_) {
            float ab = 0.f;
#pragma unroll
            for (int ww = 0; ww < 4; ++ww)
                ab = fmaf(comb_acc[ww][tid], __expf(comb_m[ww] - mb), ab);
            pp[2 + tid] = ab;
        } else if (tid == D_) {
            pp[0] = mb;
        } else {
            float lb = 0.f;
#pragma unroll
            for (int ww = 0; ww < 4; ++ww)
                lb = fmaf(comb_l[ww], __expf(comb_m[ww] - mb), lb);
            pp[1] = lb;
        }
    }
}

// ---- fused finish + e ----
__global__ __launch_bounds__(256) void
finish_e_kernel(const float* __restrict__ part, const float* __restrict__ logits,
                float* __restrict__ out) {
    const int b = blockIdx.y, s = blockIdx.x, t = threadIdx.x;
    float mb = -1e30f;
#pragma unroll
    for (int c = 0; c < CHUNKS; ++c)
        mb = fmaxf(mb, part[((size_t)b * CHUNKS + c) * 132]);
    float lb = 0.f;
#pragma unroll
    for (int c = 0; c < CHUNKS; ++c) {
        const float* pp = part + ((size_t)b * CHUNKS + c) * 132;
        lb = fmaf(pp[1], __expf(pp[0] - mb), lb);
    }
    if (s == 0 && t < D_) {
        float ac = 0.f;
#pragma unroll
        for (int c = 0; c < CHUNKS; ++c) {
            const float* pp = part + ((size_t)b * CHUNKS + c) * 132;
            ac = fmaf(pp[2 + t], __expf(pp[0] - mb), ac);
        }
        float sc = ac / lb;
        out[b * D_ + t] = (sc > 0.f) ? sc : expm1f(sc);
    }
    float inv = 1.f / lb;
    int n4 = s * 1024 + t * 4;
    float4 lg = *(const float4*)&logits[(size_t)b * N_ + n4];
    float4 e;
    e.x = __expf(lg.x - mb) * inv;
    e.y = __expf(lg.y - mb) * inv;
    e.z = __expf(lg.z - mb) * inv;
    e.w = __expf(lg.w - mb) * inv;
    *(float4*)&out[(size_t)B_ * D_ + (size_t)b * N_ + n4] = e;
}

extern "C" void kernel_launch(void* const* d_in, const int* in_sizes, int n_in,
                              void* d_out, int out_size, void* d_ws, size_t ws_size,
                              hipStream_t stream) {
    const float* query = (const float*)d_in[0];
    const float* key   = (const float*)d_in[1];
    const float* Wq    = (const float*)d_in[2];
    const float* Wk    = (const float*)d_in[3];
    const float* Wa    = (const float*)d_in[4];
    float* out = (float*)d_out;

    float* ws     = (float*)d_ws;
    float* logits = ws;                                   // B*N
    float* part   = logits + (size_t)B_ * N_;             // 32*16*132

    main_kernel<<<dim3(CHUNKS, B_), dim3(256), 0, stream>>>(
        query, key, Wq, Wk, Wa, logits, part);
    finish_e_kernel<<<dim3(16, B_), dim3(256), 0, stream>>>(part, logits, out);
}